// Round 4
// baseline (436.766 us; speedup 1.0000x reference)
//
#include <hip/hip_runtime.h>
#include <hip/hip_bf16.h>

typedef __bf16 bf16x8 __attribute__((ext_vector_type(8)));
typedef float  f32x4  __attribute__((ext_vector_type(4)));
typedef unsigned int uint4v __attribute__((ext_vector_type(4)));

#define LOG2E 1.4426950408889634f

__device__ __forceinline__ unsigned int pk2(float a, float b) {
  unsigned short lo = __builtin_bit_cast(unsigned short, (__bf16)a);
  unsigned short hi = __builtin_bit_cast(unsigned short, (__bf16)b);
  return (unsigned int)lo | ((unsigned int)hi << 16);
}

// ---------------- pred1 = (f_t @ W1^T + b1) * log2e  -> bf16 [512][128] ----
__global__ __launch_bounds__(256) void pred1_kernel(
    const float* __restrict__ f_t, const float* __restrict__ W1,
    const float* __restrict__ b1, unsigned short* __restrict__ pred1) {
  int t = blockIdx.x * 256 + threadIdx.x;   // 65536 threads
  int n = t >> 7, d = t & 127;
  const float4* fr = (const float4*)(f_t + n * 256);
  const float4* wr = (const float4*)(W1 + d * 256);
  float acc = 0.f;
#pragma unroll 16
  for (int e = 0; e < 64; ++e) {
    float4 a = fr[e], b = wr[e];
    acc += a.x * b.x; acc += a.y * b.y; acc += a.z * b.z; acc += a.w * b.w;
  }
  float v = (acc + b1[d]) * LOG2E;
  pred1[t] = __builtin_bit_cast(unsigned short, (__bf16)v);
}

// ---------------- W2 fp32 -> bf16 packed [128][128] ------------------------
__global__ __launch_bounds__(256) void w2pack_kernel(
    const float* __restrict__ W2, unsigned short* __restrict__ w2p) {
  int i = blockIdx.x * 256 + threadIdx.x;   // 16384
  w2p[i] = __builtin_bit_cast(unsigned short, (__bf16)W2[i]);
}

// -------- pred2[yx] = (fmap_t[:,y,x,:] @ W2^T + b2) * log2e -> bf16 --------
// grid 1024 = (yx, quarter); 256 threads; W2 read from L1-resident packed buf
__global__ __launch_bounds__(256, 4) void pred2_kernel(
    const float* __restrict__ fmap_t, const unsigned short* __restrict__ w2p,
    const float* __restrict__ b2, unsigned short* __restrict__ pred2) {
  const int blk = blockIdx.x;
  const int yx = blk & 255, qr = blk >> 8;
  const int tid = threadIdx.x;
  const int w = tid >> 6, lane = tid & 63;
  const int lo16 = lane & 15, hi4 = lane >> 4;
  const int rowbase = qr * 128 + w * 32;

  bf16x8 a[2][4];
#pragma unroll
  for (int mt = 0; mt < 2; ++mt)
#pragma unroll
    for (int ks = 0; ks < 4; ++ks) {
      int row = rowbase + 16 * mt + lo16;
      int k = 32 * ks + 8 * hi4;
      const float* p = fmap_t + (size_t)row * 32768 + yx * 128 + k;
      float4 f0 = ((const float4*)p)[0], f1 = ((const float4*)p)[1];
      bf16x8 av;
      av[0] = (__bf16)f0.x; av[1] = (__bf16)f0.y; av[2] = (__bf16)f0.z; av[3] = (__bf16)f0.w;
      av[4] = (__bf16)f1.x; av[5] = (__bf16)f1.y; av[6] = (__bf16)f1.z; av[7] = (__bf16)f1.w;
      a[mt][ks] = av;
    }

  unsigned short* outb = pred2 + (size_t)yx * 65536;
#pragma unroll
  for (int nt = 0; nt < 8; ++nt) {
    bf16x8 bw[4];
#pragma unroll
    for (int ks = 0; ks < 4; ++ks)
      bw[ks] = *(const bf16x8*)(w2p + (nt * 16 + lo16) * 128 + 32 * ks + 8 * hi4);
    float b2v = b2[nt * 16 + lo16];
#pragma unroll
    for (int mt = 0; mt < 2; ++mt) {
      f32x4 acc = {0.f, 0.f, 0.f, 0.f};
#pragma unroll
      for (int ks = 0; ks < 4; ++ks)
        acc = __builtin_amdgcn_mfma_f32_16x16x32_bf16(a[mt][ks], bw[ks], acc, 0, 0, 0);
      int row = rowbase + 16 * mt + hi4 * 4;
      int dcol = nt * 16 + lo16;
#pragma unroll
      for (int r = 0; r < 4; ++r) {
        float v = (acc[r] + b2v) * LOG2E;
        outb[(size_t)(row + r) * 128 + dcol] = __builtin_bit_cast(unsigned short, (__bf16)v);
      }
    }
  }
}

// ---- main: grid 1024 = (yx, half, branch); 256 pred-rows per block --------
__global__ __launch_bounds__(512, 4) void loss_kernel(
    const float* __restrict__ fmap_tp1,
    const unsigned short* __restrict__ pred1,
    const unsigned short* __restrict__ pred2,
    float* __restrict__ out) {
  __shared__ unsigned short Bs[2][8192];   // 2 x 16KB swizzled bf16 chunks (64 rows)
  const int blk = blockIdx.x;
  const int yx = blk & 255;
  const int half = (blk >> 8) & 1;
  const unsigned short* predb =
      (blk & 512) ? (pred2 + (size_t)yx * 65536) : pred1;
  const int tid = threadIdx.x;
  const int w = tid >> 6, lane = tid & 63;
  const int lo16 = lane & 15, hi4 = lane >> 4;
  const int sr = tid >> 3, sq = tid & 7;    // staging: 64 rows x 8 thr/row
  const int rbase = half * 256 + w * 32;    // this wave's pred-row base

  // A fragments: 32 rows per wave -> a[2][4] = 32 VGPRs
  bf16x8 a[2][4];
#pragma unroll
  for (int mt = 0; mt < 2; ++mt)
#pragma unroll
    for (int ks = 0; ks < 4; ++ks) {
      int row = rbase + 16 * mt + lo16;
      int k = 32 * ks + 8 * hi4;
      a[mt][ks] = *(const bf16x8*)(predb + row * 128 + k);
    }

  float s[2][4];
#pragma unroll
  for (int mt = 0; mt < 2; ++mt)
#pragma unroll
    for (int r = 0; r < 4; ++r) s[mt][r] = 0.f;
  float diag = 0.f;

  const float* srcbase = fmap_tp1 + (size_t)sr * 32768 + yx * 128 + sq * 16;
  const int wbyte0 = sr * 256 + ((sq * 32) ^ ((sr & 7) << 4));
  const int wbyte1 = sr * 256 + ((sq * 32 + 16) ^ ((sr & 7) << 4));

  float4 tmp[4];
  // stage chunk 0
#pragma unroll
  for (int j = 0; j < 4; ++j) tmp[j] = ((const float4*)srcbase)[j];
  {
    char* buf = (char*)Bs[0];
    uint4v p0 = { pk2(tmp[0].x, tmp[0].y), pk2(tmp[0].z, tmp[0].w),
                  pk2(tmp[1].x, tmp[1].y), pk2(tmp[1].z, tmp[1].w) };
    uint4v p1 = { pk2(tmp[2].x, tmp[2].y), pk2(tmp[2].z, tmp[2].w),
                  pk2(tmp[3].x, tmp[3].y), pk2(tmp[3].z, tmp[3].w) };
    *(uint4v*)(buf + wbyte0) = p0;
    *(uint4v*)(buf + wbyte1) = p1;
  }
  __syncthreads();

  for (int c = 0; c < 8; ++c) {
    if (c < 7) {   // T14: issue next chunk's global loads early
      const float4* src = (const float4*)(srcbase + (size_t)(c + 1) * 64 * 32768);
#pragma unroll
      for (int j = 0; j < 4; ++j) tmp[j] = src[j];
    }
    const char* buf = (const char*)Bs[c & 1];
#pragma unroll
    for (int nt = 0; nt < 4; ++nt) {
      bf16x8 bw[4];
#pragma unroll
      for (int ks = 0; ks < 4; ++ks) {
        int m = nt * 16 + lo16;
        int kb = (32 * ks + 8 * hi4) * 2;
        bw[ks] = *(const bf16x8*)(buf + m * 256 + (kb ^ ((m & 7) << 4)));
      }
      const int coltile = c * 64 + nt * 16;
#pragma unroll
      for (int mt = 0; mt < 2; ++mt) {
        f32x4 acc = {0.f, 0.f, 0.f, 0.f};
#pragma unroll
        for (int ks = 0; ks < 4; ++ks)
          acc = __builtin_amdgcn_mfma_f32_16x16x32_bf16(a[mt][ks], bw[ks], acc, 0, 0, 0);
#pragma unroll
        for (int r = 0; r < 4; ++r) s[mt][r] += __builtin_amdgcn_exp2f(acc[r]);
        if (coltile == rbase + mt * 16) {   // diagonal tile (wave-uniform)
#pragma unroll
          for (int r = 0; r < 4; ++r)
            if (lo16 == hi4 * 4 + r) diag += acc[r];
        }
      }
    }
    if (c < 7) {   // write next chunk into the other buffer
      char* buf2 = (char*)Bs[(c + 1) & 1];
      uint4v p0 = { pk2(tmp[0].x, tmp[0].y), pk2(tmp[0].z, tmp[0].w),
                    pk2(tmp[1].x, tmp[1].y), pk2(tmp[1].z, tmp[1].w) };
      uint4v p1 = { pk2(tmp[2].x, tmp[2].y), pk2(tmp[2].z, tmp[2].w),
                    pk2(tmp[3].x, tmp[3].y), pk2(tmp[3].z, tmp[3].w) };
      *(uint4v*)(buf2 + wbyte0) = p0;
      *(uint4v*)(buf2 + wbyte1) = p1;
    }
    __syncthreads();
  }

  // ---- reduction: sum partial sumexp across each 16-lane col group ----
  float part = 0.f;
#pragma unroll
  for (int mt = 0; mt < 2; ++mt)
#pragma unroll
    for (int r = 0; r < 4; ++r) {
      float v = s[mt][r];
#pragma unroll
      for (int m = 1; m < 16; m <<= 1) v += __shfl_xor(v, m, 64);
      if (lo16 == 0) part += __builtin_amdgcn_logf(v);
    }
  part -= diag;   // log2 units; scale by ln2 at the end
#pragma unroll
  for (int m = 1; m < 64; m <<= 1) part += __shfl_xor(part, m, 64);

  __syncthreads();               // all waves done with Bs before reuse
  float* red = (float*)Bs;
  if (lane == 0) red[w] = part;
  __syncthreads();
  if (tid == 0) {
    float t = 0.f;
#pragma unroll
    for (int i = 0; i < 8; ++i) t += red[i];
    atomicAdd(out, t * (float)(0.69314718055994530942 / 131072.0));
  }
}

extern "C" void kernel_launch(void* const* d_in, const int* in_sizes, int n_in,
                              void* d_out, int out_size, void* d_ws, size_t ws_size,
                              hipStream_t stream) {
  const float* f_t      = (const float*)d_in[0];
  const float* fmap_t   = (const float*)d_in[1];
  const float* fmap_tp1 = (const float*)d_in[2];
  const float* W1       = (const float*)d_in[3];
  const float* b1       = (const float*)d_in[4];
  const float* W2       = (const float*)d_in[5];
  const float* b2       = (const float*)d_in[6];

  unsigned short* pred1 = (unsigned short*)d_ws;            // 512*128 bf16
  unsigned short* pred2 = pred1 + 512 * 128;                // 256*512*128 bf16
  unsigned short* w2p   = pred2 + (size_t)256 * 512 * 128;  // 128*128 bf16
  float* out = (float*)d_out;

  hipMemsetAsync(out, 0, sizeof(float), stream);
  pred1_kernel<<<256, 256, 0, stream>>>(f_t, W1, b1, pred1);
  w2pack_kernel<<<64, 256, 0, stream>>>(W2, w2p);
  pred2_kernel<<<1024, 256, 0, stream>>>(fmap_t, w2p, b2, pred2);
  loss_kernel<<<1024, 512, 0, stream>>>(fmap_tp1, pred1, pred2, out);
}

// Round 5
// 232.685 us; speedup vs baseline: 1.8771x; 1.8771x over previous
//
#include <hip/hip_runtime.h>
#include <hip/hip_bf16.h>

typedef __bf16 bf16x8 __attribute__((ext_vector_type(8)));
typedef float  f32x4  __attribute__((ext_vector_type(4)));
typedef unsigned int uint4v __attribute__((ext_vector_type(4)));
typedef unsigned int uint2v __attribute__((ext_vector_type(2)));

#define LOG2E 1.4426950408889634f

__device__ __forceinline__ unsigned int pk2(float a, float b) {
  unsigned short lo = __builtin_bit_cast(unsigned short, (__bf16)a);
  unsigned short hi = __builtin_bit_cast(unsigned short, (__bf16)b);
  return (unsigned int)lo | ((unsigned int)hi << 16);
}

__device__ __forceinline__ void gl_lds16(const void* g, void* l) {
  __builtin_amdgcn_global_load_lds(
      (const __attribute__((address_space(1))) unsigned int*)g,
      (__attribute__((address_space(3))) unsigned int*)l, 16, 0, 0);
}

// ---------------- pred1 = (f_t @ W1^T + b1) * log2e  -> bf16 [512][128] ----
__global__ __launch_bounds__(256) void pred1_kernel(
    const float* __restrict__ f_t, const float* __restrict__ W1,
    const float* __restrict__ b1, unsigned short* __restrict__ pred1) {
  int t = blockIdx.x * 256 + threadIdx.x;   // 65536 threads
  int n = t >> 7, d = t & 127;
  const float4* fr = (const float4*)(f_t + n * 256);
  const float4* wr = (const float4*)(W1 + d * 256);
  float acc = 0.f;
#pragma unroll 16
  for (int e = 0; e < 64; ++e) {
    float4 a = fr[e], b = wr[e];
    acc += a.x * b.x; acc += a.y * b.y; acc += a.z * b.z; acc += a.w * b.w;
  }
  float v = (acc + b1[d]) * LOG2E;
  pred1[t] = __builtin_bit_cast(unsigned short, (__bf16)v);
}

// ---------------- W2 fp32 -> bf16 packed [128][128] ------------------------
__global__ __launch_bounds__(256) void w2pack_kernel(
    const float* __restrict__ W2, unsigned short* __restrict__ w2p) {
  int i = blockIdx.x * 256 + threadIdx.x;   // 16384
  w2p[i] = __builtin_bit_cast(unsigned short, (__bf16)W2[i]);
}

// ---- fmap_tp1 fp32 [512][yx][128] -> bf16 [yx][512][128], 16B-swizzled ----
// swizzle: within each 256B row n, byte kb -> kb ^ ((n&7)<<4)  (T2/m173:
// linear global_load_lds then reproduces the swizzled LDS layout)
__global__ __launch_bounds__(256) void tp1cvt_kernel(
    const float* __restrict__ fmap_tp1, unsigned short* __restrict__ tp1b) {
  const int yx = blockIdx.x;                // 256
  const int tid = threadIdx.x;
  const int n8 = tid >> 3, q = tid & 7;     // 8 threads per row
#pragma unroll 1
  for (int it = 0; it < 16; ++it) {
    int n = it * 32 + n8;
    const float4* src = (const float4*)(fmap_tp1 + (size_t)n * 32768 + yx * 128 + q * 16);
    float4 f0 = src[0], f1 = src[1], f2 = src[2], f3 = src[3];
    uint4v pA = { pk2(f0.x, f0.y), pk2(f0.z, f0.w), pk2(f1.x, f1.y), pk2(f1.z, f1.w) };
    uint4v pB = { pk2(f2.x, f2.y), pk2(f2.z, f2.w), pk2(f3.x, f3.y), pk2(f3.z, f3.w) };
    char* dst = (char*)tp1b + (((size_t)yx * 512 + n) << 8);
    int sw = (n & 7) << 4;
    *(uint4v*)(dst + ((q * 32) ^ sw)) = pA;
    *(uint4v*)(dst + ((q * 32 + 16) ^ sw)) = pB;
  }
}

// -------- pred2[yx] = (fmap_t[:,y,x,:] @ W2^T + b2) * log2e -> bf16 --------
// Swapped operands (A=W2, B=fmap_t) so each lane holds 4 consecutive d for a
// fixed n -> 8B ds_write, then one coalesced 32KB block store.
__global__ __launch_bounds__(256, 2) void pred2_kernel(
    const float* __restrict__ fmap_t, const unsigned short* __restrict__ w2p,
    const float* __restrict__ b2, unsigned short* __restrict__ pred2) {
  __shared__ unsigned short T[128 * 136];   // [n_local][d], pitch 136 shorts (16B-aligned rows, bank-spread)
  const int blk = blockIdx.x;
  const int yx = blk & 255, qr = blk >> 8;
  const int tid = threadIdx.x;
  const int w = tid >> 6, lane = tid & 63;
  const int lo16 = lane & 15, hi4 = lane >> 4;

  // B-frags: fmap_t rows (n), 32 per wave
  bf16x8 bfr[2][4];
#pragma unroll
  for (int mt = 0; mt < 2; ++mt)
#pragma unroll
    for (int ks = 0; ks < 4; ++ks) {
      int row = qr * 128 + w * 32 + 16 * mt + lo16;
      int k = 32 * ks + 8 * hi4;
      const float* p = fmap_t + (size_t)row * 32768 + yx * 128 + k;
      float4 f0 = ((const float4*)p)[0], f1 = ((const float4*)p)[1];
      bf16x8 bv;
      bv[0] = (__bf16)f0.x; bv[1] = (__bf16)f0.y; bv[2] = (__bf16)f0.z; bv[3] = (__bf16)f0.w;
      bv[4] = (__bf16)f1.x; bv[5] = (__bf16)f1.y; bv[6] = (__bf16)f1.z; bv[7] = (__bf16)f1.w;
      bfr[mt][ks] = bv;
    }

#pragma unroll
  for (int dtile = 0; dtile < 8; ++dtile) {
    bf16x8 aw[4];
#pragma unroll
    for (int ks = 0; ks < 4; ++ks)
      aw[ks] = *(const bf16x8*)(w2p + (dtile * 16 + lo16) * 128 + 32 * ks + 8 * hi4);
    float4 b2v = *(const float4*)(b2 + dtile * 16 + hi4 * 4);
#pragma unroll
    for (int mt = 0; mt < 2; ++mt) {
      f32x4 acc = {0.f, 0.f, 0.f, 0.f};
#pragma unroll
      for (int ks = 0; ks < 4; ++ks)
        acc = __builtin_amdgcn_mfma_f32_16x16x32_bf16(aw[ks], bfr[mt][ks], acc, 0, 0, 0);
      // lane: n_local = w*32+mt*16+lo16 ; d = dtile*16+hi4*4+r
      uint2v pk = { pk2((acc[0] + b2v.x) * LOG2E, (acc[1] + b2v.y) * LOG2E),
                    pk2((acc[2] + b2v.z) * LOG2E, (acc[3] + b2v.w) * LOG2E) };
      int nloc = w * 32 + mt * 16 + lo16;
      *(uint2v*)&T[nloc * 136 + dtile * 16 + hi4 * 4] = pk;
    }
  }
  __syncthreads();
  // coalesced write: thread t -> 128B; 256 threads cover 32KB contiguous
  const int row = tid >> 1, hb = (tid & 1) * 64;
  unsigned short* dst = pred2 + (((size_t)yx * 512 + qr * 128 + row) << 7) + hb;
  const unsigned short* srcT = &T[row * 136 + hb];
#pragma unroll
  for (int j = 0; j < 8; ++j) ((uint4v*)dst)[j] = ((const uint4v*)srcT)[j];
}

// ---- main: grid 1024 = (yx, half, branch); 256 pred-rows per block --------
__global__ __launch_bounds__(512, 2) void loss_kernel(
    const unsigned short* __restrict__ tp1b,
    const unsigned short* __restrict__ pred1,
    const unsigned short* __restrict__ pred2,
    float* __restrict__ out) {
  __shared__ unsigned short Bs[2][8192];   // 2 x 16KB bf16 chunks (64 rows, swizzled)
  const int blk = blockIdx.x;
  const int yx = blk & 255;
  const int half = (blk >> 8) & 1;
  const unsigned short* predb =
      (blk & 512) ? (pred2 + ((size_t)yx << 16)) : pred1;
  const int tid = threadIdx.x;
  const int w = tid >> 6, lane = tid & 63;
  const int lo16 = lane & 15, hi4 = lane >> 4;
  const int rbase = half * 256 + w * 32;    // this wave's pred-row base

  // A fragments: 32 rows per wave -> a[2][4] = 32 VGPRs
  bf16x8 a[2][4];
#pragma unroll
  for (int mt = 0; mt < 2; ++mt)
#pragma unroll
    for (int ks = 0; ks < 4; ++ks) {
      int row = rbase + 16 * mt + lo16;
      int k = 32 * ks + 8 * hi4;
      a[mt][ks] = *(const bf16x8*)(predb + row * 128 + k);
    }

  float s[2][4];
#pragma unroll
  for (int mt = 0; mt < 2; ++mt)
#pragma unroll
    for (int r = 0; r < 4; ++r) s[mt][r] = 0.f;
  float diag = 0.f;

  const char* gyx = (const char*)tp1b + (((size_t)yx * 512) << 8);
  const int loff = (tid >> 6) * 1024;          // wave-uniform lds offset
  const int goff = loff + (tid & 63) * 16;     // per-lane global offset

  // stage chunk 0
  gl_lds16(gyx + goff, (char*)Bs[0] + loff);
  gl_lds16(gyx + 8192 + goff, (char*)Bs[0] + 8192 + loff);
  __syncthreads();

#pragma unroll 1
  for (int c = 0; c < 8; ++c) {
    if (c < 7) {   // prefetch next chunk into other buffer (in flight over MFMA)
      const char* gch = gyx + (((c + 1) << 14));
      char* lch = (char*)Bs[(c + 1) & 1];
      gl_lds16(gch + goff, lch + loff);
      gl_lds16(gch + 8192 + goff, lch + 8192 + loff);
    }
    const char* buf = (const char*)Bs[c & 1];
#pragma unroll
    for (int nt = 0; nt < 4; ++nt) {
      bf16x8 bw[4];
#pragma unroll
      for (int ks = 0; ks < 4; ++ks) {
        int m = nt * 16 + lo16;
        int kb = (32 * ks + 8 * hi4) * 2;
        bw[ks] = *(const bf16x8*)(buf + m * 256 + (kb ^ ((m & 7) << 4)));
      }
      const int coltile = c * 64 + nt * 16;
#pragma unroll
      for (int mt = 0; mt < 2; ++mt) {
        f32x4 acc = {0.f, 0.f, 0.f, 0.f};
#pragma unroll
        for (int ks = 0; ks < 4; ++ks)
          acc = __builtin_amdgcn_mfma_f32_16x16x32_bf16(a[mt][ks], bw[ks], acc, 0, 0, 0);
#pragma unroll
        for (int r = 0; r < 4; ++r) s[mt][r] += __builtin_amdgcn_exp2f(acc[r]);
        if (coltile == rbase + mt * 16) {   // diagonal tile (wave-uniform)
#pragma unroll
          for (int r = 0; r < 4; ++r)
            if (lo16 == hi4 * 4 + r) diag += acc[r];
        }
      }
    }
    __syncthreads();   // drains vmcnt -> next buffer ready
  }

  // ---- reduction: sum partial sumexp across each 16-lane col group ----
  float part = 0.f;
#pragma unroll
  for (int mt = 0; mt < 2; ++mt)
#pragma unroll
    for (int r = 0; r < 4; ++r) {
      float v = s[mt][r];
#pragma unroll
      for (int m = 1; m < 16; m <<= 1) v += __shfl_xor(v, m, 64);
      if (lo16 == 0) part += __builtin_amdgcn_logf(v);
    }
  part -= diag;   // log2 units; scale by ln2 at the end
#pragma unroll
  for (int m = 1; m < 64; m <<= 1) part += __shfl_xor(part, m, 64);

  __syncthreads();               // all waves done with Bs before reuse
  float* red = (float*)Bs;
  if (lane == 0) red[w] = part;
  __syncthreads();
  if (tid == 0) {
    float t = 0.f;
#pragma unroll
    for (int i = 0; i < 8; ++i) t += red[i];
    atomicAdd(out, t * (float)(0.69314718055994530942 / 131072.0));
  }
}

extern "C" void kernel_launch(void* const* d_in, const int* in_sizes, int n_in,
                              void* d_out, int out_size, void* d_ws, size_t ws_size,
                              hipStream_t stream) {
  const float* f_t      = (const float*)d_in[0];
  const float* fmap_t   = (const float*)d_in[1];
  const float* fmap_tp1 = (const float*)d_in[2];
  const float* W1       = (const float*)d_in[3];
  const float* b1       = (const float*)d_in[4];
  const float* W2       = (const float*)d_in[5];
  const float* b2       = (const float*)d_in[6];

  unsigned short* pred1 = (unsigned short*)d_ws;            // 512*128 bf16
  unsigned short* pred2 = pred1 + 512 * 128;                // 256*512*128 bf16
  unsigned short* w2p   = pred2 + (size_t)256 * 512 * 128;  // 128*128 bf16
  unsigned short* tp1b  = w2p + 128 * 128;                  // 256*512*128 bf16 (swizzled)
  float* out = (float*)d_out;

  hipMemsetAsync(out, 0, sizeof(float), stream);
  pred1_kernel<<<256, 256, 0, stream>>>(f_t, W1, b1, pred1);
  w2pack_kernel<<<64, 256, 0, stream>>>(W2, w2p);
  tp1cvt_kernel<<<256, 256, 0, stream>>>(fmap_tp1, tp1b);
  pred2_kernel<<<1024, 256, 0, stream>>>(fmap_t, w2p, b2, pred2);
  loss_kernel<<<1024, 512, 0, stream>>>(tp1b, pred1, pred2, out);
}